// Round 6
// baseline (395.495 us; speedup 1.0000x reference)
//
#include <hip/hip_runtime.h>
#include <math.h>

#define HW 4096

typedef __attribute__((ext_vector_type(8)))  short short8;
typedef __attribute__((ext_vector_type(16))) float f32x16;

static __device__ inline ushort f2bf(float f) {
    uint u = __builtin_bit_cast(uint, f);
    return (ushort)((u + 0x7fffu + ((u >> 16) & 1u)) >> 16);
}
static __device__ inline float lof(uint u) { return __builtin_bit_cast(float, u << 16); }
static __device__ inline float hif(uint u) { return __builtin_bit_cast(float, u & 0xffff0000u); }

// ---------------- k0: x [b][c][h][w] f32 -> x_t [b][h][w][c] bf16 ----------------
__global__ __launch_bounds__(256) void k0_xt(const float* __restrict__ x, ushort* __restrict__ xt)
{
    const int blk = blockIdx.x;              // b*128 + h*2 + chalf
    const int b = blk >> 7, h = (blk & 127) >> 1, ch = blk & 1;
    __shared__ ushort tile[64 * 130];
    const float* xb = x + ((size_t)(b * 256 + ch * 128)) * HW + h * 64;
    const int t = threadIdx.x;
    for (int e = t; e < 8192; e += 256) {
        const int c = e >> 6, j = e & 63;
        tile[j * 130 + c] = f2bf(xb[c * HW + j]);
    }
    __syncthreads();
    for (int e = t; e < 4096; e += 256) {
        const int j = e >> 6, q = e & 63;
        uint* xo = (uint*)(xt + ((size_t)b * HW + h * 64 + j) * 256 + ch * 128);
        xo[q] = *(const uint*)&tile[j * 130 + 2 * q];
    }
}

// ---------------- k0w: weight prep ----------------
// bid<256:  w_dcn [d][c][3][3] -> wT2 [k][g=c/8][d][c%8] bf16
// bid>=256: w_off [oc][c][3][3] -> wA2 [k][g][oc_pad32][c%8] bf16
__global__ __launch_bounds__(256) void k0_w(const float* __restrict__ w_dcn,
    const float* __restrict__ w_off, ushort* __restrict__ wT2, ushort* __restrict__ wA2)
{
    const int bid = blockIdx.x;
    const int t = threadIdx.x;
    if (bid < 256) {
        const int d = bid;
        __shared__ float wl[2304];
        for (int i = t; i < 2304; i += 256) wl[i] = w_dcn[d * 2304 + i];
        __syncthreads();
        for (int i = t; i < 2304; i += 256) {
            const int k = i >> 8, c = i & 255;
            wT2[((k * 32 + (c >> 3)) * 256 + d) * 8 + (c & 7)] = f2bf(wl[c * 9 + k]);
        }
    } else {
        const int e = (bid - 256) * 256 + t;     // 73728 = 9*32*32*8
        const int k = e >> 13, r = e & 8191;
        const int g = r >> 8, oc = (r >> 3) & 31, ci = r & 7;
        const int c = g * 8 + ci;
        wA2[e] = f2bf(oc < 27 ? w_off[(oc * 256 + c) * 9 + k] : 0.f);
    }
}

// ---------------- k1: offset conv, 32x32x16 MFMA, B gathered in-reg, A from global ----------------
// block = (b, h, w-half); 256 thr = 4 K-quarter waves; wave = 32oc x 32w x 576K
__global__ __launch_bounds__(256, 4) void k1_mfma(const ushort* __restrict__ xt,
    const ushort* __restrict__ wA2, const float* __restrict__ b_off,
    float* __restrict__ offs, float* __restrict__ mk)
{
    const int bid = blockIdx.x;
    const int b = bid >> 7, h = (bid >> 1) & 63, wh = bid & 1;
    const int t = threadIdx.x;
    const int lane = t & 63, cq = t >> 6;
    const int l31 = lane & 31, khi = lane >> 5;
    const int w = wh * 32 + l31;

    __shared__ float red[3 * 1024];

    f32x16 acc = {};
    const char* xc = (const char*)(xt + ((size_t)b * HW) * 256);

#pragma unroll 1
    for (int k = 0; k < 9; ++k) {
        const int hh = h + 2 * (k / 3 - 1);
        const int ww = w + 2 * (k % 3 - 1);
        const bool ok = ((unsigned)hh < 64u) && ((unsigned)ww < 64u);
        const int base = (min(max(hh, 0), 63) * 64 + min(max(ww, 0), 63)) * 512;
#pragma unroll
        for (int j = 0; j < 4; ++j) {
            const int c0 = cq * 64 + j * 16;
            const int cb = c0 * 2 + khi * 16;
            short8 bv = *(const short8*)(xc + base + cb);
            if (!ok) bv = (short8){0, 0, 0, 0, 0, 0, 0, 0};
            const short8 av = *(const short8*)(wA2 + ((k * 32 + (c0 >> 3) + khi) * 32 + l31) * 8);
            acc = __builtin_amdgcn_mfma_f32_32x32x16_bf16(av, bv, acc, 0, 0, 0);
        }
    }

    if (cq > 0) {
#pragma unroll
        for (int r = 0; r < 16; ++r) red[(cq - 1) * 1024 + lane * 16 + r] = acc[r];
    }
    __syncthreads();
    if (cq == 0) {
#pragma unroll
        for (int r = 0; r < 16; ++r) {
            float v = acc[r] + red[lane * 16 + r] + red[1024 + lane * 16 + r] + red[2048 + lane * 16 + r];
            const int oc = (r & 3) + 8 * (r >> 2) + 4 * khi;
            v += b_off[min(oc, 26)];
            const int hw = h * 64 + w;
            if (oc < 18) {
                offs[((size_t)b * 18 + oc) * HW + hw] = fminf(fmaxf(v, -64.f), 64.f);
            } else if (oc < 27) {
                mk[((size_t)b * 9 + (oc - 18)) * HW + hw] = 1.f / (1.f + expf(-v));
            }
        }
    }
}

// ---------------- k2: fused sampling + MFMA GEMM ----------------
// block = (b, h, d-quarter); 512 thr = 8 waves = 2 w-grp x 4 K-quarter.
// wave = 64d x 32w x (9 taps x 64c). B sampled in-register; A staged in LDS per tap.
__global__ __launch_bounds__(512, 4) void k2_dcn(const ushort* __restrict__ xt, const ushort* __restrict__ wT2,
    const float* __restrict__ offs, const float* __restrict__ mk, float* __restrict__ out)
{
    const int bid = blockIdx.x;
    const int wg = (bid & 7) * 128 + (bid >> 3);     // XCD-bijective swizzle (1024 = 8*128)
    const int b = wg >> 8, h = (wg >> 2) & 63, dq = wg & 3;
    const int t = threadIdx.x;
    const int lane = t & 63, wv = t >> 6;
    const int wgrp = wv >> 2, cq = wv & 3;
    const int l31 = lane & 31, khi = lane >> 5;
    const int w = wgrp * 32 + l31;

    __shared__ __align__(16) ushort Alds[16384];     // [g 32][dl 64][8c] = 32 KB; reused for reduce

    const char* xc = (const char*)(xt + ((size_t)b * HW) * 256);
    const float* offb = offs + (size_t)b * 18 * HW + h * 64;
    const float* mkb  = mk   + (size_t)b *  9 * HW + h * 64;

    f32x16 acc[2] = {{}, {}};

    auto issueA = [&](int k) {
#pragma unroll
        for (int r = 0; r < 4; ++r) {
            const ushort* src = wT2 + ((size_t)k * 8192 + (size_t)(r * 8 + wv) * 256 + dq * 64 + lane) * 8;
            __builtin_amdgcn_global_load_lds(src, Alds + r * 4096 + t * 8, 16, 0, 0);
        }
    };

    issueA(0);

#pragma unroll 1
    for (int k = 0; k < 9; ++k) {
        __syncthreads();                             // drains global_load_lds (+ joins)
        // per-lane sampling meta for pixel w, tap k
        const float dy = offb[(2 * k) * HW + w];
        const float dx = offb[(2 * k + 1) * HW + w];
        const float mval = mkb[k * HW + w];
        const float py = (float)(h - 1 + k / 3) + dy;
        const float px = (float)(w - 1 + k % 3) + dx;
        const float y0f = floorf(py), x0f = floorf(px);
        const float wy = py - y0f, wx = px - x0f;
        const int y0 = (int)y0f, x0 = (int)x0f;
        float w00 = (1.f - wy) * (1.f - wx) * mval, w01 = (1.f - wy) * wx * mval;
        float w10 = wy * (1.f - wx) * mval,         w11 = wy * wx * mval;
        const bool vy0 = (unsigned)y0 < 64u, vy1 = (unsigned)(y0 + 1) < 64u;
        const bool vx0 = (unsigned)x0 < 64u, vx1 = (unsigned)(x0 + 1) < 64u;
        if (!(vy0 && vx0)) w00 = 0.f;
        if (!(vy0 && vx1)) w01 = 0.f;
        if (!(vy1 && vx0)) w10 = 0.f;
        if (!(vy1 && vx1)) w11 = 0.f;
        const int y0c = min(max(y0, 0), 63), y1c = min(max(y0 + 1, 0), 63);
        const int x0c = min(max(x0, 0), 63), x1c = min(max(x0 + 1, 0), 63);
        const int o00 = (y0c * 64 + x0c) * 512, o01 = (y0c * 64 + x1c) * 512;
        const int o10 = (y1c * 64 + x0c) * 512, o11 = (y1c * 64 + x1c) * 512;

#pragma unroll
        for (int j = 0; j < 4; ++j) {
            const int c0 = cq * 64 + j * 16;
            const int cb = c0 * 2 + khi * 16;
            const uint4 v00 = *(const uint4*)(xc + o00 + cb);
            const uint4 v01 = *(const uint4*)(xc + o01 + cb);
            const uint4 v10 = *(const uint4*)(xc + o10 + cb);
            const uint4 v11 = *(const uint4*)(xc + o11 + cb);
            const uint a00[4] = {v00.x, v00.y, v00.z, v00.w};
            const uint a01[4] = {v01.x, v01.y, v01.z, v01.w};
            const uint a10[4] = {v10.x, v10.y, v10.z, v10.w};
            const uint a11[4] = {v11.x, v11.y, v11.z, v11.w};
            uint rq[4];
#pragma unroll
            for (int q = 0; q < 4; ++q) {
                float lo = w00 * lof(a00[q]);
                lo = fmaf(w01, lof(a01[q]), lo);
                lo = fmaf(w10, lof(a10[q]), lo);
                lo = fmaf(w11, lof(a11[q]), lo);
                float hi = w00 * hif(a00[q]);
                hi = fmaf(w01, hif(a01[q]), hi);
                hi = fmaf(w10, hif(a10[q]), hi);
                hi = fmaf(w11, hif(a11[q]), hi);
                asm("v_cvt_pk_bf16_f32 %0, %1, %2" : "=v"(rq[q]) : "v"(lo), "v"(hi));
            }
            short8 bfrag;
#pragma unroll
            for (int q = 0; q < 4; ++q) {
                bfrag[2 * q]     = (short)(rq[q] & 0xffffu);
                bfrag[2 * q + 1] = (short)(rq[q] >> 16);
            }
            const int gk = cq * 8 + j * 2 + khi;
            const short8 a0 = *(const short8*)(Alds + (gk * 64 + l31) * 8);
            const short8 a1 = *(const short8*)(Alds + (gk * 64 + 32 + l31) * 8);
            acc[0] = __builtin_amdgcn_mfma_f32_32x32x16_bf16(a0, bfrag, acc[0], 0, 0, 0);
            acc[1] = __builtin_amdgcn_mfma_f32_32x32x16_bf16(a1, bfrag, acc[1], 0, 0, 0);
        }
        __syncthreads();                             // all waves done reading Alds
        if (k < 8) issueA(k + 1);
    }

    // K-quarter reduce via LDS (reuse Alds as float scratch, 24 KB), one df per round
    float* redf = (float*)Alds;
    float* ob = out + ((size_t)b * 256) * HW + h * 64;
#pragma unroll 1
    for (int df = 0; df < 2; ++df) {
        __syncthreads();
        if (cq > 0) {
#pragma unroll
            for (int r = 0; r < 16; ++r)
                redf[((cq - 1) * 2 + wgrp) * 1024 + lane * 16 + r] = acc[df][r];
        }
        __syncthreads();
        if (cq == 0) {
#pragma unroll
            for (int r = 0; r < 16; ++r) {
                const float v = acc[df][r] + redf[wgrp * 1024 + lane * 16 + r]
                              + redf[(2 + wgrp) * 1024 + lane * 16 + r]
                              + redf[(4 + wgrp) * 1024 + lane * 16 + r];
                const int d = dq * 64 + df * 32 + (r & 3) + 8 * (r >> 2) + 4 * khi;
                ob[(size_t)d * HW + w] = v;
            }
        }
    }
}

// ---------------- k3: GroupNorm stats per (b,g) ----------------
__global__ __launch_bounds__(256) void k3_stats(const float* __restrict__ out, float* __restrict__ stats)
{
    const int bg = blockIdx.x;
    const float* p = out + (size_t)bg * 32768;
    float s = 0.f, s2 = 0.f;
    for (int i = threadIdx.x; i < 8192; i += 256) {
        float4 v = ((const float4*)p)[i];
        s  += v.x + v.y + v.z + v.w;
        s2 += v.x * v.x + v.y * v.y + v.z * v.z + v.w * v.w;
    }
    __shared__ float r1[256], r2[256];
    r1[threadIdx.x] = s; r2[threadIdx.x] = s2;
    __syncthreads();
    for (int st = 128; st > 0; st >>= 1) {
        if (threadIdx.x < st) {
            r1[threadIdx.x] += r1[threadIdx.x + st];
            r2[threadIdx.x] += r2[threadIdx.x + st];
        }
        __syncthreads();
    }
    if (threadIdx.x == 0) {
        const float mean = r1[0] / 32768.f;
        const float var  = r2[0] / 32768.f - mean * mean;
        stats[bg * 2]     = mean;
        stats[bg * 2 + 1] = rsqrtf(var + 1e-5f);
    }
}

// ---------------- k4: normalize + affine + SiLU ----------------
__global__ __launch_bounds__(256) void k4_gn(float* __restrict__ out,
    const float* __restrict__ stats, const float* __restrict__ gamma, const float* __restrict__ beta)
{
    const int i4 = blockIdx.x * 256 + threadIdx.x;
    const int elem = i4 << 2;
    const int b = elem >> 20;
    const int ch = (elem >> 12) & 255;
    const int g = ch >> 3;
    const float mean = stats[(b * 32 + g) * 2];
    const float rstd = stats[(b * 32 + g) * 2 + 1];
    const float ga = gamma[ch], be = beta[ch];
    float4 v = ((float4*)out)[i4];
    float vv[4] = {v.x, v.y, v.z, v.w};
#pragma unroll
    for (int j = 0; j < 4; ++j) {
        const float o = (vv[j] - mean) * rstd * ga + be;
        vv[j] = o / (1.f + expf(-o));
    }
    ((float4*)out)[i4] = make_float4(vv[0], vv[1], vv[2], vv[3]);
}

extern "C" void kernel_launch(void* const* d_in, const int* in_sizes, int n_in,
                              void* d_out, int out_size, void* d_ws, size_t ws_size,
                              hipStream_t stream)
{
    const float* x     = (const float*)d_in[0];
    const float* w_off = (const float*)d_in[1];
    const float* b_off = (const float*)d_in[2];
    const float* w_dcn = (const float*)d_in[3];
    const float* gamma = (const float*)d_in[4];
    const float* beta  = (const float*)d_in[5];
    float* out = (float*)d_out;

    // ws layout: xt bf16 (8 MB) | offs | mk | stats | wT2 bf16 | wA2 bf16
    ushort* xt    = (ushort*)d_ws;
    float*  offs  = (float*)d_ws + 2097152;
    float*  mk    = offs + 294912;
    float*  stats = mk + 147456;
    ushort* wT2   = (ushort*)(stats + 256);
    ushort* wA2   = wT2 + 589824;

    hipLaunchKernelGGL(k0_xt,    dim3(512),  dim3(256), 0, stream, x, xt);
    hipLaunchKernelGGL(k0_w,     dim3(544),  dim3(256), 0, stream, w_dcn, w_off, wT2, wA2);
    hipLaunchKernelGGL(k1_mfma,  dim3(512),  dim3(256), 0, stream, xt, wA2, b_off, offs, mk);
    hipLaunchKernelGGL(k2_dcn,   dim3(1024), dim3(512), 0, stream, xt, wT2, offs, mk, out);
    hipLaunchKernelGGL(k3_stats, dim3(128),  dim3(256), 0, stream, out, stats);
    hipLaunchKernelGGL(k4_gn,    dim3(4096), dim3(256), 0, stream, out, stats, gamma, beta);
}

// Round 7
// 255.882 us; speedup vs baseline: 1.5456x; 1.5456x over previous
//
#include <hip/hip_runtime.h>
#include <math.h>

#define HW 4096

typedef __attribute__((ext_vector_type(8)))  short short8;
typedef __attribute__((ext_vector_type(16))) float f32x16;

static __device__ inline ushort f2bf(float f) {
    uint u = __builtin_bit_cast(uint, f);
    return (ushort)((u + 0x7fffu + ((u >> 16) & 1u)) >> 16);
}
static __device__ inline float lof(uint u) { return __builtin_bit_cast(float, u << 16); }
static __device__ inline float hif(uint u) { return __builtin_bit_cast(float, u & 0xffff0000u); }

// ---------------- k0: x [b][c][h][w] f32 -> x_t [b][h][w][c] bf16 ----------------
__global__ __launch_bounds__(256) void k0_xt(const float* __restrict__ x, ushort* __restrict__ xt)
{
    const int blk = blockIdx.x;              // b*128 + h*2 + chalf
    const int b = blk >> 7, h = (blk & 127) >> 1, ch = blk & 1;
    __shared__ ushort tile[64 * 130];
    const float* xb = x + ((size_t)(b * 256 + ch * 128)) * HW + h * 64;
    const int t = threadIdx.x;
    for (int e = t; e < 8192; e += 256) {
        const int c = e >> 6, j = e & 63;
        tile[j * 130 + c] = f2bf(xb[c * HW + j]);
    }
    __syncthreads();
    for (int e = t; e < 4096; e += 256) {
        const int j = e >> 6, q = e & 63;
        uint* xo = (uint*)(xt + ((size_t)b * HW + h * 64 + j) * 256 + ch * 128);
        xo[q] = *(const uint*)&tile[j * 130 + 2 * q];
    }
}

// ---------------- k0w: weight prep ----------------
// bid<256:  w_dcn [d][c][3][3] -> wT2 [k][g=c/8][d][c%8] bf16
// bid>=256: w_off [oc][c][3][3] -> wA2 [k][g][oc_pad32][c%8] bf16
__global__ __launch_bounds__(256) void k0_w(const float* __restrict__ w_dcn,
    const float* __restrict__ w_off, ushort* __restrict__ wT2, ushort* __restrict__ wA2)
{
    const int bid = blockIdx.x;
    const int t = threadIdx.x;
    if (bid < 256) {
        const int d = bid;
        __shared__ float wl[2304];
        for (int i = t; i < 2304; i += 256) wl[i] = w_dcn[d * 2304 + i];
        __syncthreads();
        for (int i = t; i < 2304; i += 256) {
            const int k = i >> 8, c = i & 255;
            wT2[((k * 32 + (c >> 3)) * 256 + d) * 8 + (c & 7)] = f2bf(wl[c * 9 + k]);
        }
    } else {
        const int e = (bid - 256) * 256 + t;     // 73728 = 9*32*32*8
        const int k = e >> 13, r = e & 8191;
        const int g = r >> 8, oc = (r >> 3) & 31, ci = r & 7;
        const int c = g * 8 + ci;
        wA2[e] = f2bf(oc < 27 ? w_off[(oc * 256 + c) * 9 + k] : 0.f);
    }
}

// ---------------- k1: offset conv, 32x32x16 MFMA, B gathered in-reg, A from global ----------------
// block = (b, h, w-half); 256 thr = 4 K-quarter waves; wave = 32oc x 32w x 576K
__global__ __launch_bounds__(256, 4) void k1_mfma(const ushort* __restrict__ xt,
    const ushort* __restrict__ wA2, const float* __restrict__ b_off,
    float* __restrict__ offs, float* __restrict__ mk)
{
    const int bid = blockIdx.x;
    const int b = bid >> 7, h = (bid >> 1) & 63, wh = bid & 1;
    const int t = threadIdx.x;
    const int lane = t & 63, cq = t >> 6;
    const int l31 = lane & 31, khi = lane >> 5;
    const int w = wh * 32 + l31;

    __shared__ float red[3 * 1024];

    f32x16 acc = {};
    const char* xc = (const char*)(xt + ((size_t)b * HW) * 256);

#pragma unroll 1
    for (int k = 0; k < 9; ++k) {
        const int hh = h + 2 * (k / 3 - 1);
        const int ww = w + 2 * (k % 3 - 1);
        const bool ok = ((unsigned)hh < 64u) && ((unsigned)ww < 64u);
        const int base = (min(max(hh, 0), 63) * 64 + min(max(ww, 0), 63)) * 512;
#pragma unroll
        for (int j = 0; j < 4; ++j) {
            const int c0 = cq * 64 + j * 16;
            const int cb = c0 * 2 + khi * 16;
            short8 bv = *(const short8*)(xc + base + cb);
            if (!ok) bv = (short8){0, 0, 0, 0, 0, 0, 0, 0};
            const short8 av = *(const short8*)(wA2 + ((k * 32 + (c0 >> 3) + khi) * 32 + l31) * 8);
            acc = __builtin_amdgcn_mfma_f32_32x32x16_bf16(av, bv, acc, 0, 0, 0);
        }
    }

    if (cq > 0) {
#pragma unroll
        for (int r = 0; r < 16; ++r) red[(cq - 1) * 1024 + lane * 16 + r] = acc[r];
    }
    __syncthreads();
    if (cq == 0) {
#pragma unroll
        for (int r = 0; r < 16; ++r) {
            float v = acc[r] + red[lane * 16 + r] + red[1024 + lane * 16 + r] + red[2048 + lane * 16 + r];
            const int oc = (r & 3) + 8 * (r >> 2) + 4 * khi;
            v += b_off[min(oc, 26)];
            const int hw = h * 64 + w;
            if (oc < 18) {
                offs[((size_t)b * 18 + oc) * HW + hw] = fminf(fmaxf(v, -64.f), 64.f);
            } else if (oc < 27) {
                mk[((size_t)b * 9 + (oc - 18)) * HW + hw] = 1.f / (1.f + expf(-v));
            }
        }
    }
}

// ---------------- k2: fused sampling + MFMA GEMM ----------------
// block = (b, h, d-quarter); 512 thr = 8 waves = 2 w-grp x 4 K-quarter.
// wave = 64d x 32w x (9 taps x 64c). B sampled in-register; A staged in LDS per tap.
__global__ __launch_bounds__(512, 4) void k2_dcn(const ushort* __restrict__ xt, const ushort* __restrict__ wT2,
    const float* __restrict__ offs, const float* __restrict__ mk, float* __restrict__ out)
{
    const int bid = blockIdx.x;
    const int wg = (bid & 7) * 128 + (bid >> 3);     // XCD-bijective swizzle (1024 = 8*128)
    const int b = wg >> 8, h = (wg >> 2) & 63, dq = wg & 3;
    const int t = threadIdx.x;
    const int lane = t & 63, wv = t >> 6;
    const int wgrp = wv >> 2, cq = wv & 3;
    const int l31 = lane & 31, khi = lane >> 5;
    const int w = wgrp * 32 + l31;

    __shared__ __align__(16) ushort Alds[16384];     // [g 32][dl 64][8c] = 32 KB; reused for reduce

    const char* xc = (const char*)(xt + ((size_t)b * HW) * 256);
    const float* offb = offs + (size_t)b * 18 * HW + h * 64;
    const float* mkb  = mk   + (size_t)b *  9 * HW + h * 64;

    f32x16 acc0 = {};
    f32x16 acc1 = {};

    auto issueA = [&](int k) {
#pragma unroll
        for (int r = 0; r < 4; ++r) {
            const ushort* src = wT2 + ((size_t)k * 8192 + (size_t)(r * 8 + wv) * 256 + dq * 64 + lane) * 8;
            __builtin_amdgcn_global_load_lds(src, Alds + r * 4096 + t * 8, 16, 0, 0);
        }
    };

    issueA(0);

#pragma unroll 1
    for (int k = 0; k < 9; ++k) {
        __syncthreads();                             // drains global_load_lds (+ joins)
        // per-lane sampling meta for pixel w, tap k
        const float dy = offb[(2 * k) * HW + w];
        const float dx = offb[(2 * k + 1) * HW + w];
        const float mval = mkb[k * HW + w];
        const float py = (float)(h - 1 + k / 3) + dy;
        const float px = (float)(w - 1 + k % 3) + dx;
        const float y0f = floorf(py), x0f = floorf(px);
        const float wy = py - y0f, wx = px - x0f;
        const int y0 = (int)y0f, x0 = (int)x0f;
        float w00 = (1.f - wy) * (1.f - wx) * mval, w01 = (1.f - wy) * wx * mval;
        float w10 = wy * (1.f - wx) * mval,         w11 = wy * wx * mval;
        const bool vy0 = (unsigned)y0 < 64u, vy1 = (unsigned)(y0 + 1) < 64u;
        const bool vx0 = (unsigned)x0 < 64u, vx1 = (unsigned)(x0 + 1) < 64u;
        if (!(vy0 && vx0)) w00 = 0.f;
        if (!(vy0 && vx1)) w01 = 0.f;
        if (!(vy1 && vx0)) w10 = 0.f;
        if (!(vy1 && vx1)) w11 = 0.f;
        const int y0c = min(max(y0, 0), 63), y1c = min(max(y0 + 1, 0), 63);
        const int x0c = min(max(x0, 0), 63), x1c = min(max(x0 + 1, 0), 63);
        const int o00 = (y0c * 64 + x0c) * 512, o01 = (y0c * 64 + x1c) * 512;
        const int o10 = (y1c * 64 + x0c) * 512, o11 = (y1c * 64 + x1c) * 512;

#pragma unroll
        for (int j = 0; j < 4; ++j) {
            const int c0 = cq * 64 + j * 16;
            const int cb = c0 * 2 + khi * 16;
            const uint4 v00 = *(const uint4*)(xc + o00 + cb);
            const uint4 v01 = *(const uint4*)(xc + o01 + cb);
            const uint4 v10 = *(const uint4*)(xc + o10 + cb);
            const uint4 v11 = *(const uint4*)(xc + o11 + cb);
            const uint a00[4] = {v00.x, v00.y, v00.z, v00.w};
            const uint a01[4] = {v01.x, v01.y, v01.z, v01.w};
            const uint a10[4] = {v10.x, v10.y, v10.z, v10.w};
            const uint a11[4] = {v11.x, v11.y, v11.z, v11.w};
            uint rq[4];
#pragma unroll
            for (int q = 0; q < 4; ++q) {
                float lo = w00 * lof(a00[q]);
                lo = fmaf(w01, lof(a01[q]), lo);
                lo = fmaf(w10, lof(a10[q]), lo);
                lo = fmaf(w11, lof(a11[q]), lo);
                float hi = w00 * hif(a00[q]);
                hi = fmaf(w01, hif(a01[q]), hi);
                hi = fmaf(w10, hif(a10[q]), hi);
                hi = fmaf(w11, hif(a11[q]), hi);
                asm("v_cvt_pk_bf16_f32 %0, %1, %2" : "=v"(rq[q]) : "v"(lo), "v"(hi));
            }
            short8 bfrag;
#pragma unroll
            for (int q = 0; q < 4; ++q) {
                bfrag[2 * q]     = (short)(rq[q] & 0xffffu);
                bfrag[2 * q + 1] = (short)(rq[q] >> 16);
            }
            const int gk = cq * 8 + j * 2 + khi;
            const short8 a0 = *(const short8*)(Alds + (gk * 64 + l31) * 8);
            const short8 a1 = *(const short8*)(Alds + (gk * 64 + 32 + l31) * 8);
            acc0 = __builtin_amdgcn_mfma_f32_32x32x16_bf16(a0, bfrag, acc0, 0, 0, 0);
            acc1 = __builtin_amdgcn_mfma_f32_32x32x16_bf16(a1, bfrag, acc1, 0, 0, 0);
        }
        __syncthreads();                             // all waves done reading Alds
        if (k < 8) issueA(k + 1);
    }

    // K-quarter reduce via LDS (reuse Alds as float scratch).
    // NOTE: df loop fully unrolled -> all acc indexing is compile-time (rule #20:
    // runtime-indexed ext_vector arrays go to scratch; R6 paid 648 MB of spill traffic for this).
    float* redf = (float*)Alds;
    float* ob = out + ((size_t)b * 256) * HW + h * 64;
#pragma unroll
    for (int df = 0; df < 2; ++df) {
        const f32x16& a = (df == 0) ? acc0 : acc1;
        __syncthreads();
        if (cq > 0) {
#pragma unroll
            for (int r = 0; r < 16; ++r)
                redf[((cq - 1) * 2 + wgrp) * 1024 + lane * 16 + r] = a[r];
        }
        __syncthreads();
        if (cq == 0) {
#pragma unroll
            for (int r = 0; r < 16; ++r) {
                const float v = a[r] + redf[wgrp * 1024 + lane * 16 + r]
                              + redf[(2 + wgrp) * 1024 + lane * 16 + r]
                              + redf[(4 + wgrp) * 1024 + lane * 16 + r];
                const int d = dq * 64 + df * 32 + (r & 3) + 8 * (r >> 2) + 4 * khi;
                ob[(size_t)d * HW + w] = v;
            }
        }
    }
}

// ---------------- k3: GroupNorm stats per (b,g) ----------------
__global__ __launch_bounds__(256) void k3_stats(const float* __restrict__ out, float* __restrict__ stats)
{
    const int bg = blockIdx.x;
    const float* p = out + (size_t)bg * 32768;
    float s = 0.f, s2 = 0.f;
    for (int i = threadIdx.x; i < 8192; i += 256) {
        float4 v = ((const float4*)p)[i];
        s  += v.x + v.y + v.z + v.w;
        s2 += v.x * v.x + v.y * v.y + v.z * v.z + v.w * v.w;
    }
    __shared__ float r1[256], r2[256];
    r1[threadIdx.x] = s; r2[threadIdx.x] = s2;
    __syncthreads();
    for (int st = 128; st > 0; st >>= 1) {
        if (threadIdx.x < st) {
            r1[threadIdx.x] += r1[threadIdx.x + st];
            r2[threadIdx.x] += r2[threadIdx.x + st];
        }
        __syncthreads();
    }
    if (threadIdx.x == 0) {
        const float mean = r1[0] / 32768.f;
        const float var  = r2[0] / 32768.f - mean * mean;
        stats[bg * 2]     = mean;
        stats[bg * 2 + 1] = rsqrtf(var + 1e-5f);
    }
}

// ---------------- k4: normalize + affine + SiLU ----------------
__global__ __launch_bounds__(256) void k4_gn(float* __restrict__ out,
    const float* __restrict__ stats, const float* __restrict__ gamma, const float* __restrict__ beta)
{
    const int i4 = blockIdx.x * 256 + threadIdx.x;
    const int elem = i4 << 2;
    const int b = elem >> 20;
    const int ch = (elem >> 12) & 255;
    const int g = ch >> 3;
    const float mean = stats[(b * 32 + g) * 2];
    const float rstd = stats[(b * 32 + g) * 2 + 1];
    const float ga = gamma[ch], be = beta[ch];
    float4 v = ((float4*)out)[i4];
    float vv[4] = {v.x, v.y, v.z, v.w};
#pragma unroll
    for (int j = 0; j < 4; ++j) {
        const float o = (vv[j] - mean) * rstd * ga + be;
        vv[j] = o / (1.f + expf(-o));
    }
    ((float4*)out)[i4] = make_float4(vv[0], vv[1], vv[2], vv[3]);
}

extern "C" void kernel_launch(void* const* d_in, const int* in_sizes, int n_in,
                              void* d_out, int out_size, void* d_ws, size_t ws_size,
                              hipStream_t stream)
{
    const float* x     = (const float*)d_in[0];
    const float* w_off = (const float*)d_in[1];
    const float* b_off = (const float*)d_in[2];
    const float* w_dcn = (const float*)d_in[3];
    const float* gamma = (const float*)d_in[4];
    const float* beta  = (const float*)d_in[5];
    float* out = (float*)d_out;

    // ws layout: xt bf16 (8 MB) | offs | mk | stats | wT2 bf16 | wA2 bf16
    ushort* xt    = (ushort*)d_ws;
    float*  offs  = (float*)d_ws + 2097152;
    float*  mk    = offs + 294912;
    float*  stats = mk + 147456;
    ushort* wT2   = (ushort*)(stats + 256);
    ushort* wA2   = wT2 + 589824;

    hipLaunchKernelGGL(k0_xt,    dim3(512),  dim3(256), 0, stream, x, xt);
    hipLaunchKernelGGL(k0_w,     dim3(544),  dim3(256), 0, stream, w_dcn, w_off, wT2, wA2);
    hipLaunchKernelGGL(k1_mfma,  dim3(512),  dim3(256), 0, stream, xt, wA2, b_off, offs, mk);
    hipLaunchKernelGGL(k2_dcn,   dim3(1024), dim3(512), 0, stream, xt, wT2, offs, mk, out);
    hipLaunchKernelGGL(k3_stats, dim3(128),  dim3(256), 0, stream, out, stats);
    hipLaunchKernelGGL(k4_gn,    dim3(4096), dim3(256), 0, stream, out, stats, gamma, beta);
}

// Round 10
// 177.304 us; speedup vs baseline: 2.2306x; 1.4432x over previous
//
#include <hip/hip_runtime.h>
#include <math.h>

#define HW 4096

typedef __attribute__((ext_vector_type(8)))  short short8;
typedef __attribute__((ext_vector_type(16))) float f32x16;

static __device__ inline ushort f2bf(float f) {
    uint u = __builtin_bit_cast(uint, f);
    return (ushort)((u + 0x7fffu + ((u >> 16) & 1u)) >> 16);
}
static __device__ inline float lof(uint u) { return __builtin_bit_cast(float, u << 16); }
static __device__ inline float hif(uint u) { return __builtin_bit_cast(float, u & 0xffff0000u); }

// ---------------- k0: x [b][c][h][w] f32 -> x_t [b][h][w][c] bf16 ----------------
__global__ __launch_bounds__(256) void k0_xt(const float* __restrict__ x, ushort* __restrict__ xt)
{
    const int blk = blockIdx.x;              // b*128 + h*2 + chalf
    const int b = blk >> 7, h = (blk & 127) >> 1, ch = blk & 1;
    __shared__ ushort tile[64 * 130];
    const float* xb = x + ((size_t)(b * 256 + ch * 128)) * HW + h * 64;
    const int t = threadIdx.x;
    for (int e = t; e < 8192; e += 256) {
        const int c = e >> 6, j = e & 63;
        tile[j * 130 + c] = f2bf(xb[c * HW + j]);
    }
    __syncthreads();
    for (int e = t; e < 4096; e += 256) {
        const int j = e >> 6, q = e & 63;
        uint* xo = (uint*)(xt + ((size_t)b * HW + h * 64 + j) * 256 + ch * 128);
        xo[q] = *(const uint*)&tile[j * 130 + 2 * q];
    }
}

// ---------------- k0w: weight prep ----------------
// bid<256:  w_dcn [d][c][3][3] -> wT2 [k][g=c/8][d][c%8] bf16
// bid>=256: w_off [oc][c][3][3] -> wA2 [k][g][oc_pad32][c%8] bf16
__global__ __launch_bounds__(256) void k0_w(const float* __restrict__ w_dcn,
    const float* __restrict__ w_off, ushort* __restrict__ wT2, ushort* __restrict__ wA2)
{
    const int bid = blockIdx.x;
    const int t = threadIdx.x;
    if (bid < 256) {
        const int d = bid;
        __shared__ float wl[2304];
        for (int i = t; i < 2304; i += 256) wl[i] = w_dcn[d * 2304 + i];
        __syncthreads();
        for (int i = t; i < 2304; i += 256) {
            const int k = i >> 8, c = i & 255;
            wT2[((k * 32 + (c >> 3)) * 256 + d) * 8 + (c & 7)] = f2bf(wl[c * 9 + k]);
        }
    } else {
        const int e = (bid - 256) * 256 + t;     // 73728 = 9*32*32*8
        const int k = e >> 13, r = e & 8191;
        const int g = r >> 8, oc = (r >> 3) & 31, ci = r & 7;
        const int c = g * 8 + ci;
        wA2[e] = f2bf(oc < 27 ? w_off[(oc * 256 + c) * 9 + k] : 0.f);
    }
}

// ---------------- k1: offset conv, 32x32x16 MFMA, 8 c-eighth waves + LDS reduce ----------------
// block = (b, h, w-half); 512 thr = 8 waves; wave = 32oc x 32px x (9 taps x 32c)
__global__ __launch_bounds__(512, 4) void k1_mfma(const ushort* __restrict__ xt,
    const ushort* __restrict__ wA2, const float* __restrict__ b_off,
    float* __restrict__ offs, float* __restrict__ mk)
{
    const int bid = blockIdx.x;
    const int wg = (bid & 7) * 64 + (bid >> 3);      // XCD-bijective swizzle (512 = 8*64)
    const int b = wg >> 7, h = (wg >> 1) & 63, wh = wg & 1;
    const int t = threadIdx.x;
    const int lane = t & 63, cq = t >> 6;            // cq 0..7: c-eighth (32 ch)
    const int l31 = lane & 31, khi = lane >> 5;
    const int w = wh * 32 + l31;

    __shared__ float red[7 * 1088];                  // stride 17 per lane -> conflict-free

    f32x16 acc = {};
    const char* xc = (const char*)(xt + ((size_t)b * HW) * 256);

#pragma unroll 3
    for (int k = 0; k < 9; ++k) {
        const int hh = h + 2 * (k / 3 - 1);
        const int ww = w + 2 * (k % 3 - 1);
        const bool ok = ((unsigned)hh < 64u) && ((unsigned)ww < 64u);
        const int base = (min(max(hh, 0), 63) * 64 + min(max(ww, 0), 63)) * 512;
#pragma unroll
        for (int jj = 0; jj < 2; ++jj) {
            const int ga = cq * 4 + 2 * jj + khi;    // 16B granule index (8 ch)
            short8 bv = *(const short8*)(xc + base + ga * 16);
            if (!ok) bv = (short8){0, 0, 0, 0, 0, 0, 0, 0};
            const short8 av = *(const short8*)(wA2 + ((k * 32 + ga) * 32 + l31) * 8);
            acc = __builtin_amdgcn_mfma_f32_32x32x16_bf16(av, bv, acc, 0, 0, 0);
        }
    }

    if (cq > 0) {
#pragma unroll
        for (int r = 0; r < 16; ++r) red[(cq - 1) * 1088 + lane * 17 + r] = acc[r];
    }
    __syncthreads();
    if (cq == 0) {
#pragma unroll
        for (int r = 0; r < 16; ++r) {
            float v = acc[r];
#pragma unroll
            for (int p = 0; p < 7; ++p) v += red[p * 1088 + lane * 17 + r];
            const int oc = (r & 3) + 8 * (r >> 2) + 4 * khi;
            v += b_off[min(oc, 26)];
            const int hw = h * 64 + w;
            if (oc < 18) {
                offs[((size_t)b * 18 + oc) * HW + hw] = fminf(fmaxf(v, -64.f), 64.f);
            } else if (oc < 27) {
                mk[((size_t)b * 9 + (oc - 18)) * HW + hw] = 1.f / (1.f + expf(-v));
            }
        }
    }
}

// ---------------- k2: fused sampling + MFMA GEMM, no d-split ----------------
// block = (b,h): all 256 d x 64 px. 1024 thr = 16 waves = 8 dgrp x 2 pxgrp;
// wave = one 32x32 tile, full K = 9 taps x 256 c. acc = 1 f32x16 (no reduce).
// Per tap: B (sampled) staged ONCE in LDS (64px x 512B, slot-XOR swizzle), dbuf,
// T14 split staging (gathers issued before gemm, blend+write after), 1 barrier/tap.
// A read direct from global wT2 (L1/L2-resident).
__global__ __launch_bounds__(1024, 4) void k2_dcn(const ushort* __restrict__ xt, const ushort* __restrict__ wT2,
    const float* __restrict__ offs, const float* __restrict__ mk, float* __restrict__ out)
{
    const int bid = blockIdx.x;
    const int wg = (bid & 7) * 32 + (bid >> 3);      // XCD-bijective swizzle (256 = 8*32)
    const int b = wg >> 6, h = wg & 63;
    const int t = threadIdx.x;
    const int lane = t & 63, wv = t >> 6;
    const int dgrp = wv >> 1, pxgrp = wv & 1;
    const int l31 = lane & 31, khi = lane >> 5;

    __shared__ __align__(16) ushort S[2][16384];     // [buf][px 64][slot 32][8ch] = 64 KB
    __shared__ int4   cOff[576];
    __shared__ float4 cWgt[576];

    // ---- meta: 9 taps x 64 px ----
    if (t < 576) {
        const int k = t >> 6, px = t & 63;
        const float dy = offs[((size_t)b * 18 + 2 * k) * HW + h * 64 + px];
        const float dx = offs[((size_t)b * 18 + 2 * k + 1) * HW + h * 64 + px];
        const float mval = mk[((size_t)b * 9 + k) * HW + h * 64 + px];
        const float py = (float)(h - 1 + k / 3) + dy;
        const float px_ = (float)(px - 1 + k % 3) + dx;
        const float y0f = floorf(py), x0f = floorf(px_);
        const float wy = py - y0f, wx = px_ - x0f;
        const int y0 = (int)y0f, x0 = (int)x0f;
        float w00 = (1.f - wy) * (1.f - wx) * mval, w01 = (1.f - wy) * wx * mval;
        float w10 = wy * (1.f - wx) * mval,         w11 = wy * wx * mval;
        const bool vy0 = (unsigned)y0 < 64u, vy1 = (unsigned)(y0 + 1) < 64u;
        const bool vx0 = (unsigned)x0 < 64u, vx1 = (unsigned)(x0 + 1) < 64u;
        if (!(vy0 && vx0)) w00 = 0.f;
        if (!(vy0 && vx1)) w01 = 0.f;
        if (!(vy1 && vx0)) w10 = 0.f;
        if (!(vy1 && vx1)) w11 = 0.f;
        const int y0c = min(max(y0, 0), 63), y1c = min(max(y0 + 1, 0), 63);
        const int x0c = min(max(x0, 0), 63), x1c = min(max(x0 + 1, 0), 63);
        cOff[t] = make_int4((y0c * 64 + x0c) * 512, (y0c * 64 + x1c) * 512,
                            (y1c * 64 + x0c) * 512, (y1c * 64 + x1c) * 512);
        cWgt[t] = make_float4(w00, w01, w10, w11);
    }

    f32x16 acc = {};
    const char* xc = (const char*)(xt + ((size_t)b * HW) * 256);
    const int spx = t >> 4, ssl = t & 15;            // staging: px 0..63, 32B-slice 0..15
    const int px31 = spx & 31;

    // in-flight gather registers (T14 issue-early / write-late)
    uint4 g00a, g00b, g01a, g01b, g10a, g10b, g11a, g11b;

    auto sload = [&](int k) {
        const int4 co = cOff[k * 64 + spx];
        const int cb = ssl * 32;
        g00a = *(const uint4*)(xc + co.x + cb); g00b = *(const uint4*)(xc + co.x + cb + 16);
        g01a = *(const uint4*)(xc + co.y + cb); g01b = *(const uint4*)(xc + co.y + cb + 16);
        g10a = *(const uint4*)(xc + co.z + cb); g10b = *(const uint4*)(xc + co.z + cb + 16);
        g11a = *(const uint4*)(xc + co.w + cb); g11b = *(const uint4*)(xc + co.w + cb + 16);
    };

    auto sblend = [&](int k, int pb) {
        const float4 cw = cWgt[k * 64 + spx];
        const uint a00[8] = {g00a.x, g00a.y, g00a.z, g00a.w, g00b.x, g00b.y, g00b.z, g00b.w};
        const uint a01[8] = {g01a.x, g01a.y, g01a.z, g01a.w, g01b.x, g01b.y, g01b.z, g01b.w};
        const uint a10[8] = {g10a.x, g10a.y, g10a.z, g10a.w, g10b.x, g10b.y, g10b.z, g10b.w};
        const uint a11[8] = {g11a.x, g11a.y, g11a.z, g11a.w, g11b.x, g11b.y, g11b.z, g11b.w};
        uint r[8];
#pragma unroll
        for (int q = 0; q < 8; ++q) {
            float lo = cw.x * lof(a00[q]);
            lo = fmaf(cw.y, lof(a01[q]), lo);
            lo = fmaf(cw.z, lof(a10[q]), lo);
            lo = fmaf(cw.w, lof(a11[q]), lo);
            float hi = cw.x * hif(a00[q]);
            hi = fmaf(cw.y, hif(a01[q]), hi);
            hi = fmaf(cw.z, hif(a10[q]), hi);
            hi = fmaf(cw.w, hif(a11[q]), hi);
            asm("v_cvt_pk_bf16_f32 %0, %1, %2" : "=v"(r[q]) : "v"(lo), "v"(hi));
        }
        const int slot0 = (2 * ssl) ^ px31, slot1 = (2 * ssl + 1) ^ px31;
        *(uint4*)&S[pb][spx * 256 + slot0 * 8] = make_uint4(r[0], r[1], r[2], r[3]);
        *(uint4*)&S[pb][spx * 256 + slot1 * 8] = make_uint4(r[4], r[5], r[6], r[7]);
    };

    auto gemm = [&](int k, int pb) {
        // wT2 layout: index = ((k*32 + ga)*256 + d)*8 + ci  (shorts)
        // R9 BUGFIX: was  wT2 + k*8192 + dgrp*32 + l31  (tap stride /8, d not scaled by 8)
        const ushort* Ak = wT2 + (size_t)k * 65536 + (size_t)(dgrp * 32 + l31) * 8;
        const ushort* Sp = &S[pb][(pxgrp * 32 + l31) * 256];
#pragma unroll
        for (int ks = 0; ks < 16; ++ks) {
            const int ga = 2 * ks + khi;
            const short8 a  = *(const short8*)(Ak + (size_t)ga * 2048);
            const short8 bf = *(const short8*)(Sp + ((ga ^ l31) << 3));
            acc = __builtin_amdgcn_mfma_f32_32x32x16_bf16(a, bf, acc, 0, 0, 0);
        }
    };

    __syncthreads();                                 // meta ready
    sload(0);
    sblend(0, 0);
    __syncthreads();
#pragma unroll 1
    for (int k = 0; k < 9; ++k) {
        if (k < 8) sload(k + 1);                     // issue gathers early (latency hides under gemm)
        gemm(k, k & 1);
        if (k < 8) sblend(k + 1, (k + 1) & 1);       // consume gathers, write other buffer
        __syncthreads();
    }

    // epilogue: direct store (wave owns full K)
    float* ob = out + ((size_t)b * 256) * HW + h * 64 + pxgrp * 32 + l31;
#pragma unroll
    for (int r = 0; r < 16; ++r) {
        const int d = dgrp * 32 + (r & 3) + 8 * (r >> 2) + 4 * khi;
        ob[(size_t)d * HW] = acc[r];
    }
}

// ---------------- k3: GroupNorm stats per (b,g) ----------------
__global__ __launch_bounds__(256) void k3_stats(const float* __restrict__ out, float* __restrict__ stats)
{
    const int bg = blockIdx.x;
    const float* p = out + (size_t)bg * 32768;
    float s = 0.f, s2 = 0.f;
    for (int i = threadIdx.x; i < 8192; i += 256) {
        float4 v = ((const float4*)p)[i];
        s  += v.x + v.y + v.z + v.w;
        s2 += v.x * v.x + v.y * v.y + v.z * v.z + v.w * v.w;
    }
    __shared__ float r1[256], r2[256];
    r1[threadIdx.x] = s; r2[threadIdx.x] = s2;
    __syncthreads();
    for (int st = 128; st > 0; st >>= 1) {
        if (threadIdx.x < st) {
            r1[threadIdx.x] += r1[threadIdx.x + st];
            r2[threadIdx.x] += r2[threadIdx.x + st];
        }
        __syncthreads();
    }
    if (threadIdx.x == 0) {
        const float mean = r1[0] / 32768.f;
        const float var  = r2[0] / 32768.f - mean * mean;
        stats[bg * 2]     = mean;
        stats[bg * 2 + 1] = rsqrtf(var + 1e-5f);
    }
}

// ---------------- k4: normalize + affine + SiLU ----------------
__global__ __launch_bounds__(256) void k4_gn(float* __restrict__ out,
    const float* __restrict__ stats, const float* __restrict__ gamma, const float* __restrict__ beta)
{
    const int i4 = blockIdx.x * 256 + threadIdx.x;
    const int elem = i4 << 2;
    const int b = elem >> 20;
    const int ch = (elem >> 12) & 255;
    const int g = ch >> 3;
    const float mean = stats[(b * 32 + g) * 2];
    const float rstd = stats[(b * 32 + g) * 2 + 1];
    const float ga = gamma[ch], be = beta[ch];
    float4 v = ((float4*)out)[i4];
    float vv[4] = {v.x, v.y, v.z, v.w};
#pragma unroll
    for (int j = 0; j < 4; ++j) {
        const float o = (vv[j] - mean) * rstd * ga + be;
        vv[j] = o / (1.f + expf(-o));
    }
    ((float4*)out)[i4] = make_float4(vv[0], vv[1], vv[2], vv[3]);
}

extern "C" void kernel_launch(void* const* d_in, const int* in_sizes, int n_in,
                              void* d_out, int out_size, void* d_ws, size_t ws_size,
                              hipStream_t stream)
{
    const float* x     = (const float*)d_in[0];
    const float* w_off = (const float*)d_in[1];
    const float* b_off = (const float*)d_in[2];
    const float* w_dcn = (const float*)d_in[3];
    const float* gamma = (const float*)d_in[4];
    const float* beta  = (const float*)d_in[5];
    float* out = (float*)d_out;

    // ws layout: xt bf16 (8 MB) | offs | mk | stats | wT2 bf16 | wA2 bf16
    ushort* xt    = (ushort*)d_ws;
    float*  offs  = (float*)d_ws + 2097152;
    float*  mk    = offs + 294912;
    float*  stats = mk + 147456;
    ushort* wT2   = (ushort*)(stats + 256);
    ushort* wA2   = wT2 + 589824;

    hipLaunchKernelGGL(k0_xt,    dim3(512),  dim3(256),  0, stream, x, xt);
    hipLaunchKernelGGL(k0_w,     dim3(544),  dim3(256),  0, stream, w_dcn, w_off, wT2, wA2);
    hipLaunchKernelGGL(k1_mfma,  dim3(512),  dim3(512),  0, stream, xt, wA2, b_off, offs, mk);
    hipLaunchKernelGGL(k2_dcn,   dim3(256),  dim3(1024), 0, stream, xt, wT2, offs, mk, out);
    hipLaunchKernelGGL(k3_stats, dim3(128),  dim3(256),  0, stream, out, stats);
    hipLaunchKernelGGL(k4_gn,    dim3(4096), dim3(256),  0, stream, out, stats, gamma, beta);
}